// Round 19
// baseline (435.996 us; speedup 1.0000x reference)
//
#include <hip/hip_runtime.h>
#include <math.h>

#define NPTS 50000
#define NG   128
#define DD   32
#define FF   64
#define AA   8
#define HINC 1120   // DD + FF + 2*FF*AA
#define EPSV 1e-5f
#define CH   64
#define NT   512

__device__ __forceinline__ float tanh_fast(float x) {
    float e = __expf(-2.f * fabsf(x));
    float r = __fdividef(1.f - e, 1.f + e);
    return copysignf(r, x);
}

// embed one row's 4 dims (8-lane group cooperates via shfl_xor) — r16/r17-verified
__device__ __forceinline__ void embed4(const float* __restrict__ x,
                                       const float* __restrict__ Wi,
                                       const float* __restrict__ bi,
                                       const float* __restrict__ lniw,
                                       const float* __restrict__ lnib,
                                       int n, int d4,
                                       float& o0, float& o1, float& o2, float& o3) {
    float x0 = x[n*3], x1 = x[n*3+1], x2 = x[n*3+2];
    float tv0 = x0*Wi[d4+0] + x1*Wi[DD+d4+0] + x2*Wi[2*DD+d4+0] + bi[d4+0];
    float tv1 = x0*Wi[d4+1] + x1*Wi[DD+d4+1] + x2*Wi[2*DD+d4+1] + bi[d4+1];
    float tv2 = x0*Wi[d4+2] + x1*Wi[DD+d4+2] + x2*Wi[2*DD+d4+2] + bi[d4+2];
    float tv3 = x0*Wi[d4+3] + x1*Wi[DD+d4+3] + x2*Wi[2*DD+d4+3] + bi[d4+3];
    float sm = (tv0+tv1) + (tv2+tv3);
    sm += __shfl_xor(sm, 1); sm += __shfl_xor(sm, 2); sm += __shfl_xor(sm, 4);
    float mm = sm * (1.f/DD);
    float c0 = tv0-mm, c1 = tv1-mm, c2 = tv2-mm, c3 = tv3-mm;
    float qq = (c0*c0 + c1*c1) + (c2*c2 + c3*c3);
    qq += __shfl_xor(qq, 1); qq += __shfl_xor(qq, 2); qq += __shfl_xor(qq, 4);
    float inv = 1.f/sqrtf(qq*(1.f/DD) + EPSV);
    o0 = tanh_fast(c0*inv*lniw[d4+0] + lnib[d4+0]);
    o1 = tanh_fast(c1*inv*lniw[d4+1] + lnib[d4+1]);
    o2 = tanh_fast(c2*inv*lniw[d4+2] + lnib[d4+2]);
    o3 = tanh_fast(c3*inv*lniw[d4+3] + lnib[d4+3]);
}

// ---------------------------------------------------------------- setup: offs + stats zero + Weff/beff fold
__global__ __launch_bounds__(256) void k_setup(const int* __restrict__ batch,
                                               const float* __restrict__ W_in,
                                               const float* __restrict__ b_in,
                                               const float* __restrict__ W_out,
                                               const float* __restrict__ b_out,
                                               int* __restrict__ offs,
                                               float* __restrict__ stats,
                                               float* __restrict__ Weff,
                                               float* __restrict__ beff) {
    int t = threadIdx.x, bid = blockIdx.x;
    if (bid == 0) {
        if (t <= NG) {
            int lo = 0, hi = NPTS;
            while (lo < hi) { int mid = (lo+hi)>>1; if (batch[mid] < t) lo = mid+1; else hi = mid; }
            offs[t] = lo;
        }
        if (t < 32) stats[t] = 0.f;
    } else {
        int j = bid - 1;
        const float* W0 = W_out + (size_t)j*HINC*DD;   // rows 0..31
        const float* W1 = W0 + DD*DD;                  // rows 32..95
        const float* Wi = W_in + (size_t)j*DD*FF;
        for (int e = t; e < DD*DD; e += 256) {
            int i = e >> 5, d = e & 31;
            float s = W0[e];
            for (int f = 0; f < FF; f++) s += Wi[i*FF+f] * W1[f*DD+d];
            Weff[j*DD*DD + e] = s;
        }
        if (t < DD) {
            float s = b_out[j*DD + t];
            for (int f = 0; f < FF; f++) s += b_in[j*FF+f] * W1[f*DD+t];
            beff[j*DD + t] = s;
        }
    }
}

// ---------------------------------------------------------------- k_L: one kernel/layer, one 512-thread block/graph
// Pass-1 is barrier-free: products accumulated in 64+64 register cells per thread.
__global__ __launch_bounds__(NT, 1) void k_L(const float* __restrict__ x,
                                             const float* __restrict__ Wi,
                                             const float* __restrict__ bi,
                                             const float* __restrict__ lniw,
                                             const float* __restrict__ lnib,
                                             const float* __restrict__ inb,
                                             const float* __restrict__ stats,
                                             const float* __restrict__ gw,
                                             const float* __restrict__ gb,
                                             const float* __restrict__ Win,
                                             const float* __restrict__ bin,
                                             const float* __restrict__ Wsc,
                                             const float* __restrict__ bsc,
                                             const int* __restrict__ offs,
                                             const float* __restrict__ Wagg,  // W_out[j] + 96*DD
                                             const float* __restrict__ beff,
                                             const float* __restrict__ Weff,
                                             float* __restrict__ tbuf,
                                             float* __restrict__ statsO,
                                             int isL0) {
    int g = blockIdx.x;
    int gs = offs[g], cnt = offs[g+1] - gs;
    const int t = threadIdx.x;
    if (cnt <= 0) return;                     // uniform, before any sync

    __shared__ float sWin[DD*FF];             // 8192 B
    __shared__ float sScT[AA*FF];             // 2048 B   Wsc transposed [a][f]
    __shared__ float sW[DD][36];              // 4608 B   (gln-scaled for L>=1)
    __shared__ float stageS[8][512];          // 16384 B  per-wave cell sums
    __shared__ float stageM[8][512];          // 16384 B  per-wave cell maxes
    __shared__ float agg[2*FF*AA];            // 4096 B
    __shared__ float red[16][DD];             // 2048 B
    __shared__ float aggWs[DD];
    __shared__ float sbin[FF];
    __shared__ float shW[DD];
    __shared__ float rs1[8], rs2[8];

    ((float4*)sWin)[t] = ((const float4*)Win)[t];              // 512 f4 = 2048 floats
    { int a = t >> 6, f = t & 63; sScT[t] = Wsc[f*AA + a]; }   // 512 == AA*FF
    for (int k = t; k < DD*DD; k += NT) sW[k >> 5][k & 31] = Weff[k];

    float gm = 0.f, ginv = 1.f;
    if (!isL0) {
        const float invM = 1.f/((float)NPTS*DD);
        gm = stats[0]*invM;
        float var = stats[1]*invM - gm*gm;
        ginv = 1.f/(sqrtf(fmaxf(var, 0.f)) + EPSV);
    }
    __syncthreads();                          // raw weights staged
    if (!isL0) {
        if (t < FF) {                         // bin' = bin + shift@Win (raw)
            float b = bin[t];
            for (int k = 0; k < DD; k++) {
                float sk = ginv * gw[k];
                float sh = gb[k] - gm * sk;
                b += sh * sWin[k*FF + t];
            }
            sbin[t] = b;
        } else if (t < FF + DD) {
            int d = t - FF;
            float r = 0.f;
            for (int k = 0; k < DD; k++) {
                float sk = ginv * gw[k];
                float sh = gb[k] - gm * sk;
                r += sh * sW[k][d];
            }
            shW[d] = r;
        }
        __syncthreads();                      // bin'/shW done reading raw weights
        for (int e = t; e < DD*FF; e += NT) sWin[e] *= ginv * gw[e >> 6];
        for (int e = t; e < DD*DD; e += NT) sW[e >> 5][e & 31] *= ginv * gw[e >> 5];
        __syncthreads();
    } else {
        if (t < FF) sbin[t] = bin[t];
        else if (t < FF + DD) shW[t - FF] = 0.f;
        __syncthreads();
    }

    const int pt = t >> 3, q = t & 7;
    const int fo = q * 8, d4 = q * 4;
    const int ca = t >> 6, cf = t & 63;
    const float4 bi0 = *(const float4*)&sbin[fo];
    const float4 bi1 = *(const float4*)&sbin[fo+4];
    float bscr[8];
    #pragma unroll
    for (int a = 0; a < 8; a++) bscr[a] = bsc[a];

    // per-thread cell accumulators: cells (a, fo+j)
    float asum[64], amax[64];
    #pragma unroll
    for (int i = 0; i < 64; i++) { asum[i] = 0.f; amax[i] = -INFINITY; }

    // ================= pass 1 (barrier-free): rows -> xp/attn -> register cells =================
    float4 cur[8], nxt[8];
    {   // preload chunk 0 row
        int np0 = min(CH, cnt);
        if (isL0) {
            if (pt < np0) {
                float o0,o1,o2,o3;
                embed4(x, Wi, bi, lniw, lnib, gs + pt, d4, o0,o1,o2,o3);
                #pragma unroll
                for (int j = 0; j < 8; j++) {
                    int src = (t & 56) | j;
                    cur[j].x = __shfl(o0, src, 64); cur[j].y = __shfl(o1, src, 64);
                    cur[j].z = __shfl(o2, src, 64); cur[j].w = __shfl(o3, src, 64);
                }
            }
        } else {
            int n0 = gs + min(pt, cnt-1);
            const float4* r4 = (const float4*)(inb + (size_t)n0*DD);
            #pragma unroll
            for (int j = 0; j < 8; j++) cur[j] = r4[j];
        }
    }
    for (int base = gs; base < gs + cnt; base += CH) {
        int np = min(CH, gs + cnt - base);
        int nb = base + CH;
        if (nb < gs + cnt) {                  // prefetch/pre-embed next chunk row
            if (isL0) {
                int np1 = min(CH, gs + cnt - nb);
                if (pt < np1) {
                    float o0,o1,o2,o3;
                    embed4(x, Wi, bi, lniw, lnib, nb + pt, d4, o0,o1,o2,o3);
                    #pragma unroll
                    for (int j = 0; j < 8; j++) {
                        int src = (t & 56) | j;
                        nxt[j].x = __shfl(o0, src, 64); nxt[j].y = __shfl(o1, src, 64);
                        nxt[j].z = __shfl(o2, src, 64); nxt[j].w = __shfl(o3, src, 64);
                    }
                }
            } else {
                int nclamp = min(nb + pt, gs + cnt - 1);
                const float4* r4 = (const float4*)(inb + (size_t)nclamp*DD);
                #pragma unroll
                for (int j = 0; j < 8; j++) nxt[j] = r4[j];
            }
        }
        if (pt < np) {
            float xr[8] = {bi0.x,bi0.y,bi0.z,bi0.w,bi1.x,bi1.y,bi1.z,bi1.w};
            #pragma unroll
            for (int k4 = 0; k4 < 8; k4++) {
                float hv0 = cur[k4].x, hv1 = cur[k4].y, hv2 = cur[k4].z, hv3 = cur[k4].w;
                int kb = k4*4;
                float4 wa, wb;
                wa = *(const float4*)&sWin[(kb+0)*FF + fo]; wb = *(const float4*)&sWin[(kb+0)*FF + fo + 4];
                xr[0]+=hv0*wa.x; xr[1]+=hv0*wa.y; xr[2]+=hv0*wa.z; xr[3]+=hv0*wa.w;
                xr[4]+=hv0*wb.x; xr[5]+=hv0*wb.y; xr[6]+=hv0*wb.z; xr[7]+=hv0*wb.w;
                wa = *(const float4*)&sWin[(kb+1)*FF + fo]; wb = *(const float4*)&sWin[(kb+1)*FF + fo + 4];
                xr[0]+=hv1*wa.x; xr[1]+=hv1*wa.y; xr[2]+=hv1*wa.z; xr[3]+=hv1*wa.w;
                xr[4]+=hv1*wb.x; xr[5]+=hv1*wb.y; xr[6]+=hv1*wb.z; xr[7]+=hv1*wb.w;
                wa = *(const float4*)&sWin[(kb+2)*FF + fo]; wb = *(const float4*)&sWin[(kb+2)*FF + fo + 4];
                xr[0]+=hv2*wa.x; xr[1]+=hv2*wa.y; xr[2]+=hv2*wa.z; xr[3]+=hv2*wa.w;
                xr[4]+=hv2*wb.x; xr[5]+=hv2*wb.y; xr[6]+=hv2*wb.z; xr[7]+=hv2*wb.w;
                wa = *(const float4*)&sWin[(kb+3)*FF + fo]; wb = *(const float4*)&sWin[(kb+3)*FF + fo + 4];
                xr[0]+=hv3*wa.x; xr[1]+=hv3*wa.y; xr[2]+=hv3*wa.z; xr[3]+=hv3*wa.w;
                xr[4]+=hv3*wb.x; xr[5]+=hv3*wb.y; xr[6]+=hv3*wb.z; xr[7]+=hv3*wb.w;
            }
            float pa[8];
            #pragma unroll
            for (int a = 0; a < 8; a++) {
                float4 wa = *(const float4*)&sScT[a*FF + fo];
                float4 wb = *(const float4*)&sScT[a*FF + fo + 4];
                pa[a] = xr[0]*wa.x + xr[1]*wa.y + xr[2]*wa.z + xr[3]*wa.w
                      + xr[4]*wb.x + xr[5]*wb.y + xr[6]*wb.z + xr[7]*wb.w;
            }
            #pragma unroll
            for (int msk = 1; msk < 8; msk <<= 1) {
                #pragma unroll
                for (int a = 0; a < 8; a++) pa[a] += __shfl_xor(pa[a], msk);
            }
            // all 8 attn values in-register; accumulate 64 products into cells
            #pragma unroll
            for (int a = 0; a < 8; a++) {
                float atv = __expf(-fabsf(pa[a] + bscr[a]));
                #pragma unroll
                for (int j = 0; j < 8; j++) {
                    float w = atv * xr[j];
                    asum[a*8+j] += w;
                    amax[a*8+j] = fmaxf(amax[a*8+j], w);
                }
            }
        }
        #pragma unroll
        for (int j = 0; j < 8; j++) cur[j] = nxt[j];
    }

    // ================= reduce cells: in-wave (same-q lanes) then cross-wave via LDS =================
    #pragma unroll
    for (int msk = 8; msk <= 32; msk <<= 1) {
        #pragma unroll
        for (int i = 0; i < 64; i++) {
            asum[i] += __shfl_xor(asum[i], msk);
            amax[i] = fmaxf(amax[i], __shfl_xor(amax[i], msk));
        }
    }
    {   // lanes with pt==0 (one per q per wave) publish their wave's cells
        int wv = t >> 6;
        if ((t & 56) == 0) {
            int qq = t & 7;
            #pragma unroll
            for (int a = 0; a < 8; a++) {
                #pragma unroll
                for (int j = 0; j < 8; j++) {
                    stageS[wv][a*FF + qq*8 + j] = asum[a*8+j];
                    stageM[wv][a*FF + qq*8 + j] = amax[a*8+j];
                }
            }
        }
    }
    __syncthreads();
    {   // final combine per cell (ca,cf)
        float sum = 0.f, mx = -INFINITY;
        #pragma unroll
        for (int wv = 0; wv < 8; wv++) {
            sum += stageS[wv][ca*FF + cf];
            mx = fmaxf(mx, stageM[wv][ca*FF + cf]);
        }
        agg[ca*2*FF + cf]      = sum / (float)cnt;
        agg[ca*2*FF + FF + cf] = mx;
    }
    __syncthreads();

    // ================= fold B: agg -> aggWs (once per graph) =================
    {
        int d = t & 31, grp = t >> 5;             // 16 groups x 64 k
        float acc = 0.f;
        #pragma unroll
        for (int k2 = 0; k2 < 64; k2++) {
            int k = grp*64 + k2;
            acc += agg[k] * Wagg[k*DD + d];
        }
        red[grp][d] = acc;
    }
    __syncthreads();
    if (t < DD) {
        float r = 0.f;
        #pragma unroll
        for (int qq = 0; qq < 16; qq++) r += red[qq][t];
        aggWs[t] = r + beff[t] + shW[t];
    }
    __syncthreads();                              // aggWs visible

    // ================= pass 2 (barrier-free): out = tanh(row@sW + aggWs) =================
    float s1 = 0.f, s2a = 0.f;
    if (pt < cnt) {
        float4 a0 = *(const float4*)&aggWs[d4];
        if (isL0) {
            for (int n = gs + pt; n < gs + cnt; n += CH) {
                float o0,o1,o2,o3;
                embed4(x, Wi, bi, lniw, lnib, n, d4, o0,o1,o2,o3);
                float4 row[8];
                #pragma unroll
                for (int j = 0; j < 8; j++) {
                    int src = (t & 56) | j;
                    row[j].x = __shfl(o0, src, 64); row[j].y = __shfl(o1, src, 64);
                    row[j].z = __shfl(o2, src, 64); row[j].w = __shfl(o3, src, 64);
                }
                float acc0 = a0.x, acc1 = a0.y, acc2 = a0.z, acc3 = a0.w;
                #pragma unroll
                for (int k4 = 0; k4 < 8; k4++) {
                    float hv0 = row[k4].x, hv1 = row[k4].y, hv2 = row[k4].z, hv3 = row[k4].w;
                    int kb = k4*4;
                    float4 w;
                    w = *(const float4*)&sW[kb+0][d4];
                    acc0 += hv0*w.x; acc1 += hv0*w.y; acc2 += hv0*w.z; acc3 += hv0*w.w;
                    w = *(const float4*)&sW[kb+1][d4];
                    acc0 += hv1*w.x; acc1 += hv1*w.y; acc2 += hv1*w.z; acc3 += hv1*w.w;
                    w = *(const float4*)&sW[kb+2][d4];
                    acc0 += hv2*w.x; acc1 += hv2*w.y; acc2 += hv2*w.z; acc3 += hv2*w.w;
                    w = *(const float4*)&sW[kb+3][d4];
                    acc0 += hv3*w.x; acc1 += hv3*w.y; acc2 += hv3*w.z; acc3 += hv3*w.w;
                }
                float4 o;
                o.x = tanh_fast(acc0); o.y = tanh_fast(acc1);
                o.z = tanh_fast(acc2); o.w = tanh_fast(acc3);
                *(float4*)&tbuf[(size_t)n*DD + d4] = o;
                s1  += (o.x + o.y) + (o.z + o.w);
                s2a += (o.x*o.x + o.y*o.y) + (o.z*o.z + o.w*o.w);
            }
        } else {
            float4 rcur[8], rnxt[8];
            {
                const float4* r4 = (const float4*)(inb + (size_t)(gs + pt)*DD);
                #pragma unroll
                for (int j = 0; j < 8; j++) rcur[j] = r4[j];
            }
            for (int n = gs + pt; n < gs + cnt; n += CH) {
                int nn = n + CH;
                int nclamp = (nn < gs + cnt) ? nn : n;
                {
                    const float4* r4 = (const float4*)(inb + (size_t)nclamp*DD);
                    #pragma unroll
                    for (int j = 0; j < 8; j++) rnxt[j] = r4[j];
                }
                float acc0 = a0.x, acc1 = a0.y, acc2 = a0.z, acc3 = a0.w;
                #pragma unroll
                for (int k4 = 0; k4 < 8; k4++) {
                    float hv0 = rcur[k4].x, hv1 = rcur[k4].y, hv2 = rcur[k4].z, hv3 = rcur[k4].w;
                    int kb = k4*4;
                    float4 w;
                    w = *(const float4*)&sW[kb+0][d4];
                    acc0 += hv0*w.x; acc1 += hv0*w.y; acc2 += hv0*w.z; acc3 += hv0*w.w;
                    w = *(const float4*)&sW[kb+1][d4];
                    acc0 += hv1*w.x; acc1 += hv1*w.y; acc2 += hv1*w.z; acc3 += hv1*w.w;
                    w = *(const float4*)&sW[kb+2][d4];
                    acc0 += hv2*w.x; acc1 += hv2*w.y; acc2 += hv2*w.z; acc3 += hv2*w.w;
                    w = *(const float4*)&sW[kb+3][d4];
                    acc0 += hv3*w.x; acc1 += hv3*w.y; acc2 += hv3*w.z; acc3 += hv3*w.w;
                }
                float4 o;
                o.x = tanh_fast(acc0); o.y = tanh_fast(acc1);
                o.z = tanh_fast(acc2); o.w = tanh_fast(acc3);
                *(float4*)&tbuf[(size_t)n*DD + d4] = o;
                s1  += (o.x + o.y) + (o.z + o.w);
                s2a += (o.x*o.x + o.y*o.y) + (o.z*o.z + o.w*o.w);
                #pragma unroll
                for (int j = 0; j < 8; j++) rcur[j] = rnxt[j];
            }
        }
    }
    // stats reduce -> one atomic pair per block
    #pragma unroll
    for (int o = 32; o > 0; o >>= 1) { s1 += __shfl_down(s1, o); s2a += __shfl_down(s2a, o); }
    int wid = t >> 6;
    __syncthreads();
    if ((t & 63) == 0) { rs1[wid] = s1; rs2[wid] = s2a; }
    __syncthreads();
    if (t == 0) {
        float a1 = 0.f, a2 = 0.f;
        #pragma unroll
        for (int qq = 0; qq < 8; qq++) { a1 += rs1[qq]; a2 += rs2[qq]; }
        atomicAdd(&statsO[0], a1);
        atomicAdd(&statsO[1], a2);
    }
}

// ---------------------------------------------------------------- readout: segment mean of gln(tbuf) -> 3x (dense+ln+tanh) -> dot
__global__ __launch_bounds__(256) void k_read(const float* __restrict__ tbuf,
                                              const float* __restrict__ stats,
                                              const float* __restrict__ gw,
                                              const float* __restrict__ gb,
                                              const int* __restrict__ offs,
                                              const float* __restrict__ Wp,
                                              const float* __restrict__ bp,
                                              const float* __restrict__ lnw,
                                              const float* __restrict__ lnb,
                                              const float* __restrict__ Wpo,
                                              const float* __restrict__ bpo,
                                              float* __restrict__ out) {
    int g = blockIdx.x;
    int t = threadIdx.x;
    int d = t & 31, pl = t >> 5;   // 8 point-lanes x 32 dims
    int s0 = offs[g], e0 = offs[g+1];
    float acc = 0.f;
    for (int n = s0 + pl; n < e0; n += 8) acc += tbuf[(size_t)n*DD + d];
    __shared__ float red[8][DD];
    red[pl][d] = acc;
    __syncthreads();
    __shared__ float sv[DD];
    if (t < DD) {
        float r = 0.f;
        #pragma unroll
        for (int qq = 0; qq < 8; qq++) r += red[qq][t];
        const float invM = 1.f/((float)NPTS*DD);
        float m = stats[0]*invM;
        float var = stats[1]*invM - m*m;
        float inv = 1.f/(sqrtf(fmaxf(var, 0.f)) + EPSV);
        float cnt = (float)(e0 - s0);
        float mean = r / fmaxf(cnt, 1.f);
        sv[t] = (e0 > s0) ? (mean - m)*inv*gw[t] + gb[t] : 0.f;
    }
    __syncthreads();
    for (int j = 0; j < 3; j++) {
        float yv = 0.f;
        if (t < DD) {
            float y = bp[j*DD + t];
            #pragma unroll
            for (int i = 0; i < DD; i++) y += sv[i] * Wp[j*DD*DD + i*DD + t];
            float sum = y;
            #pragma unroll
            for (int o = 1; o < 32; o <<= 1) sum += __shfl_xor(sum, o);
            float m = sum * (1.f/DD);
            float c = y - m;
            float sq = c*c;
            #pragma unroll
            for (int o = 1; o < 32; o <<= 1) sq += __shfl_xor(sq, o);
            float var = sq * (1.f/DD);
            yv = tanh_fast(c / sqrtf(var + EPSV) * lnw[j*DD+t] + lnb[j*DD+t]);
        }
        __syncthreads();
        if (t < DD) sv[t] = yv;
        __syncthreads();
    }
    if (t < DD) {
        float p = sv[t] * Wpo[t];
        #pragma unroll
        for (int o = 1; o < 32; o <<= 1) p += __shfl_xor(p, o);
        if (t == 0) out[g] = p + bpo[0];
    }
}

extern "C" void kernel_launch(void* const* d_in, const int* in_sizes, int n_in,
                              void* d_out, int out_size, void* d_ws, size_t ws_size,
                              hipStream_t stream) {
    const float* x     = (const float*)d_in[0];
    const int*   batch = (const int*)  d_in[1];
    const float* Wi    = (const float*)d_in[2];
    const float* bi    = (const float*)d_in[3];
    const float* lni_w = (const float*)d_in[4];
    const float* lni_b = (const float*)d_in[5];
    const float* W_in  = (const float*)d_in[6];
    const float* b_in  = (const float*)d_in[7];
    const float* W_sc  = (const float*)d_in[8];
    const float* b_sc  = (const float*)d_in[9];
    const float* W_out = (const float*)d_in[10];
    const float* b_out = (const float*)d_in[11];
    const float* gln_w = (const float*)d_in[12];
    const float* gln_b = (const float*)d_in[13];
    const float* Wp    = (const float*)d_in[14];
    const float* bp    = (const float*)d_in[15];
    const float* lnp_w = (const float*)d_in[16];
    const float* lnp_b = (const float*)d_in[17];
    const float* Wpo   = (const float*)d_in[18];
    const float* bpo   = (const float*)d_in[19];
    float* out = (float*)d_out;

    float* ws    = (float*)d_ws;
    float* tbuf  = ws;                                  // NPTS*32
    float* stats = tbuf + (size_t)NPTS*DD;              // 32
    float* Weff  = stats + 32;                          // 3*1024
    float* beff  = Weff + 3*DD*DD;                      // 96
    int*   offs  = (int*)(beff + 3*DD);                 // NG+1

    k_setup<<<4, 256, 0, stream>>>(batch, W_in, b_in, W_out, b_out, offs, stats, Weff, beff);

    for (int L = 0; L < 9; ++L) {
        int j = L % 3;
        int pj = (L + 2) % 3;
        const float* st  = L ? stats + 2*(L-1) : nullptr;
        const float* pgw = L ? gln_w + pj*DD : nullptr;
        const float* pgb = L ? gln_b + pj*DD : nullptr;
        k_L<<<NG, NT, 0, stream>>>(
            x, Wi, bi, lni_w, lni_b,
            tbuf, st, pgw, pgb,
            W_in + (size_t)j*DD*FF, b_in + j*FF,
            W_sc + (size_t)j*FF*AA, b_sc + j*AA,
            offs,
            W_out + (size_t)j*HINC*DD + (size_t)96*DD, beff + j*DD,
            Weff + (size_t)j*DD*DD, tbuf, stats + 2*L, (L == 0) ? 1 : 0);
    }
    k_read<<<NG, 256, 0, stream>>>(tbuf, stats + 16, gln_w + 2*DD, gln_b + 2*DD,
                                   offs, Wp, bp, lnp_w, lnp_b, Wpo, bpo, out);
}

// Round 20
// 348.800 us; speedup vs baseline: 1.2500x; 1.2500x over previous
//
#include <hip/hip_runtime.h>
#include <math.h>

#define NPTS 50000
#define NG   128
#define DD   32
#define FF   64
#define AA   8
#define HINC 1120   // DD + FF + 2*FF*AA
#define EPSV 1e-5f
#define CH   64
#define NT   512

__device__ __forceinline__ float tanh_fast(float x) {
    float e = __expf(-2.f * fabsf(x));
    float r = __fdividef(1.f - e, 1.f + e);
    return copysignf(r, x);
}

// embed one row's 4 dims (8-lane group cooperates via shfl_xor) — r16/r17-verified
__device__ __forceinline__ void embed4(const float* __restrict__ x,
                                       const float* __restrict__ Wi,
                                       const float* __restrict__ bi,
                                       const float* __restrict__ lniw,
                                       const float* __restrict__ lnib,
                                       int n, int d4,
                                       float& o0, float& o1, float& o2, float& o3) {
    float x0 = x[n*3], x1 = x[n*3+1], x2 = x[n*3+2];
    float tv0 = x0*Wi[d4+0] + x1*Wi[DD+d4+0] + x2*Wi[2*DD+d4+0] + bi[d4+0];
    float tv1 = x0*Wi[d4+1] + x1*Wi[DD+d4+1] + x2*Wi[2*DD+d4+1] + bi[d4+1];
    float tv2 = x0*Wi[d4+2] + x1*Wi[DD+d4+2] + x2*Wi[2*DD+d4+2] + bi[d4+2];
    float tv3 = x0*Wi[d4+3] + x1*Wi[DD+d4+3] + x2*Wi[2*DD+d4+3] + bi[d4+3];
    float sm = (tv0+tv1) + (tv2+tv3);
    sm += __shfl_xor(sm, 1); sm += __shfl_xor(sm, 2); sm += __shfl_xor(sm, 4);
    float mm = sm * (1.f/DD);
    float c0 = tv0-mm, c1 = tv1-mm, c2 = tv2-mm, c3 = tv3-mm;
    float qq = (c0*c0 + c1*c1) + (c2*c2 + c3*c3);
    qq += __shfl_xor(qq, 1); qq += __shfl_xor(qq, 2); qq += __shfl_xor(qq, 4);
    float inv = 1.f/sqrtf(qq*(1.f/DD) + EPSV);
    o0 = tanh_fast(c0*inv*lniw[d4+0] + lnib[d4+0]);
    o1 = tanh_fast(c1*inv*lniw[d4+1] + lnib[d4+1]);
    o2 = tanh_fast(c2*inv*lniw[d4+2] + lnib[d4+2]);
    o3 = tanh_fast(c3*inv*lniw[d4+3] + lnib[d4+3]);
}

// ---------------------------------------------------------------- setup: offs + stats zero + Weff/beff fold
__global__ __launch_bounds__(256) void k_setup(const int* __restrict__ batch,
                                               const float* __restrict__ W_in,
                                               const float* __restrict__ b_in,
                                               const float* __restrict__ W_out,
                                               const float* __restrict__ b_out,
                                               int* __restrict__ offs,
                                               float* __restrict__ stats,
                                               float* __restrict__ Weff,
                                               float* __restrict__ beff) {
    int t = threadIdx.x, bid = blockIdx.x;
    if (bid == 0) {
        if (t <= NG) {
            int lo = 0, hi = NPTS;
            while (lo < hi) { int mid = (lo+hi)>>1; if (batch[mid] < t) lo = mid+1; else hi = mid; }
            offs[t] = lo;
        }
        if (t < 32) stats[t] = 0.f;
    } else {
        int j = bid - 1;
        const float* W0 = W_out + (size_t)j*HINC*DD;   // rows 0..31
        const float* W1 = W0 + DD*DD;                  // rows 32..95
        const float* Wi = W_in + (size_t)j*DD*FF;
        for (int e = t; e < DD*DD; e += 256) {
            int i = e >> 5, d = e & 31;
            float s = W0[e];
            for (int f = 0; f < FF; f++) s += Wi[i*FF+f] * W1[f*DD+d];
            Weff[j*DD*DD + e] = s;
        }
        if (t < DD) {
            float s = b_out[j*DD + t];
            for (int f = 0; f < FF; f++) s += b_in[j*FF+f] * W1[f*DD+t];
            beff[j*DD + t] = s;
        }
    }
}

// ---------------------------------------------------------------- k_L: one kernel/layer, one 512-thread block/graph
// r14 structure + double-buffered pass-1 (1 barrier/chunk) + unified embed4 L0 path
__global__ __launch_bounds__(NT, 1) void k_L(const float* __restrict__ x,
                                             const float* __restrict__ Wi,
                                             const float* __restrict__ bi,
                                             const float* __restrict__ lniw,
                                             const float* __restrict__ lnib,
                                             const float* __restrict__ inb,
                                             const float* __restrict__ stats,
                                             const float* __restrict__ gw,
                                             const float* __restrict__ gb,
                                             const float* __restrict__ Win,
                                             const float* __restrict__ bin,
                                             const float* __restrict__ Wsc,
                                             const float* __restrict__ bsc,
                                             const int* __restrict__ offs,
                                             const float* __restrict__ Wagg,  // W_out[j] + 96*DD
                                             const float* __restrict__ beff,
                                             const float* __restrict__ Weff,
                                             float* __restrict__ tbuf,
                                             float* __restrict__ statsO,
                                             int isL0) {
    int g = blockIdx.x;
    int gs = offs[g], cnt = offs[g+1] - gs;
    const int t = threadIdx.x;
    if (cnt <= 0) return;                     // uniform, before any sync

    __shared__ float sxp[2][CH][68];          // 34816 B, double-buffered, padded
    __shared__ float sattn[2][CH][9];         // 4608 B
    __shared__ float sWin[DD*FF];             // 8192 B
    __shared__ float sScT[AA*FF];             // 2048 B   Wsc transposed [a][f]
    __shared__ float sW[DD][36];              // 4608 B   (gln-scaled for L>=1)
    __shared__ float agg[2*FF*AA];            // 4096 B
    __shared__ float red[16][DD];             // 2048 B
    __shared__ float aggWs[DD];
    __shared__ float sbin[FF];
    __shared__ float shW[DD];
    __shared__ float rs1[8], rs2[8];

    ((float4*)sWin)[t] = ((const float4*)Win)[t];              // 512 f4 = 2048 floats
    { int a = t >> 6, f = t & 63; sScT[t] = Wsc[f*AA + a]; }   // 512 == AA*FF
    for (int k = t; k < DD*DD; k += NT) sW[k >> 5][k & 31] = Weff[k];

    float gm = 0.f, ginv = 1.f;
    if (!isL0) {
        const float invM = 1.f/((float)NPTS*DD);
        gm = stats[0]*invM;
        float var = stats[1]*invM - gm*gm;
        ginv = 1.f/(sqrtf(fmaxf(var, 0.f)) + EPSV);
    }
    __syncthreads();                          // raw weights staged
    if (!isL0) {
        if (t < FF) {                         // bin' = bin + shift@Win (raw)
            float b = bin[t];
            for (int k = 0; k < DD; k++) {
                float sk = ginv * gw[k];
                float sh = gb[k] - gm * sk;
                b += sh * sWin[k*FF + t];
            }
            sbin[t] = b;
        } else if (t < FF + DD) {
            int d = t - FF;
            float r = 0.f;
            for (int k = 0; k < DD; k++) {
                float sk = ginv * gw[k];
                float sh = gb[k] - gm * sk;
                r += sh * sW[k][d];
            }
            shW[d] = r;
        }
        __syncthreads();                      // bin'/shW done reading raw weights
        for (int e = t; e < DD*FF; e += NT) sWin[e] *= ginv * gw[e >> 6];
        for (int e = t; e < DD*DD; e += NT) sW[e >> 5][e & 31] *= ginv * gw[e >> 5];
        __syncthreads();
    } else {
        if (t < FF) sbin[t] = bin[t];
        else if (t < FF + DD) shW[t - FF] = 0.f;
        __syncthreads();
    }

    const int pt = t >> 3, q = t & 7;
    const int fo = q * 8, d4 = q * 4;
    const int ca = t >> 6, cf = t & 63;
    const float bscv = bsc[q];
    const float4 bi0 = *(const float4*)&sbin[fo];
    const float4 bi1 = *(const float4*)&sbin[fo+4];
    float csum = 0.f, cmax = -INFINITY;

    // ================= pass 1: rows -> xp/attn -> register agg cells =================
    // double-buffered: ONE barrier per chunk (phase2(i+1)@buf[(i+1)&1] vs phase3(i)@buf[i&1] — disjoint)
    float4 cur[8], nxt[8];
    {   // preload chunk 0 row
        int np0 = min(CH, cnt);
        if (isL0) {
            if (pt < np0) {
                float o0,o1,o2,o3;
                embed4(x, Wi, bi, lniw, lnib, gs + pt, d4, o0,o1,o2,o3);
                #pragma unroll
                for (int j = 0; j < 8; j++) {
                    int src = (t & 56) | j;
                    cur[j].x = __shfl(o0, src, 64); cur[j].y = __shfl(o1, src, 64);
                    cur[j].z = __shfl(o2, src, 64); cur[j].w = __shfl(o3, src, 64);
                }
            }
        } else {
            int n0 = gs + min(pt, cnt-1);
            const float4* r4 = (const float4*)(inb + (size_t)n0*DD);
            #pragma unroll
            for (int j = 0; j < 8; j++) cur[j] = r4[j];
        }
    }
    int parity = 0;
    for (int base = gs; base < gs + cnt; base += CH, parity ^= 1) {
        int np = min(CH, gs + cnt - base);
        int nb = base + CH;
        if (nb < gs + cnt) {                  // prefetch/pre-embed next chunk row
            if (isL0) {
                int np1 = min(CH, gs + cnt - nb);
                if (pt < np1) {
                    float o0,o1,o2,o3;
                    embed4(x, Wi, bi, lniw, lnib, nb + pt, d4, o0,o1,o2,o3);
                    #pragma unroll
                    for (int j = 0; j < 8; j++) {
                        int src = (t & 56) | j;
                        nxt[j].x = __shfl(o0, src, 64); nxt[j].y = __shfl(o1, src, 64);
                        nxt[j].z = __shfl(o2, src, 64); nxt[j].w = __shfl(o3, src, 64);
                    }
                }
            } else {
                int nclamp = min(nb + pt, gs + cnt - 1);
                const float4* r4 = (const float4*)(inb + (size_t)nclamp*DD);
                #pragma unroll
                for (int j = 0; j < 8; j++) nxt[j] = r4[j];
            }
        }
        // ---- phase 2: xp + attn -> buf[parity]
        if (pt < np) {
            float xr[8] = {bi0.x,bi0.y,bi0.z,bi0.w,bi1.x,bi1.y,bi1.z,bi1.w};
            #pragma unroll
            for (int k4 = 0; k4 < 8; k4++) {
                float hv0 = cur[k4].x, hv1 = cur[k4].y, hv2 = cur[k4].z, hv3 = cur[k4].w;
                int kb = k4*4;
                float4 wa, wb;
                wa = *(const float4*)&sWin[(kb+0)*FF + fo]; wb = *(const float4*)&sWin[(kb+0)*FF + fo + 4];
                xr[0]+=hv0*wa.x; xr[1]+=hv0*wa.y; xr[2]+=hv0*wa.z; xr[3]+=hv0*wa.w;
                xr[4]+=hv0*wb.x; xr[5]+=hv0*wb.y; xr[6]+=hv0*wb.z; xr[7]+=hv0*wb.w;
                wa = *(const float4*)&sWin[(kb+1)*FF + fo]; wb = *(const float4*)&sWin[(kb+1)*FF + fo + 4];
                xr[0]+=hv1*wa.x; xr[1]+=hv1*wa.y; xr[2]+=hv1*wa.z; xr[3]+=hv1*wa.w;
                xr[4]+=hv1*wb.x; xr[5]+=hv1*wb.y; xr[6]+=hv1*wb.z; xr[7]+=hv1*wb.w;
                wa = *(const float4*)&sWin[(kb+2)*FF + fo]; wb = *(const float4*)&sWin[(kb+2)*FF + fo + 4];
                xr[0]+=hv2*wa.x; xr[1]+=hv2*wa.y; xr[2]+=hv2*wa.z; xr[3]+=hv2*wa.w;
                xr[4]+=hv2*wb.x; xr[5]+=hv2*wb.y; xr[6]+=hv2*wb.z; xr[7]+=hv2*wb.w;
                wa = *(const float4*)&sWin[(kb+3)*FF + fo]; wb = *(const float4*)&sWin[(kb+3)*FF + fo + 4];
                xr[0]+=hv3*wa.x; xr[1]+=hv3*wa.y; xr[2]+=hv3*wa.z; xr[3]+=hv3*wa.w;
                xr[4]+=hv3*wb.x; xr[5]+=hv3*wb.y; xr[6]+=hv3*wb.z; xr[7]+=hv3*wb.w;
            }
            float pa[8];
            #pragma unroll
            for (int a = 0; a < 8; a++) {
                float4 wa = *(const float4*)&sScT[a*FF + fo];
                float4 wb = *(const float4*)&sScT[a*FF + fo + 4];
                pa[a] = xr[0]*wa.x + xr[1]*wa.y + xr[2]*wa.z + xr[3]*wa.w
                      + xr[4]*wb.x + xr[5]*wb.y + xr[6]*wb.z + xr[7]*wb.w;
            }
            #pragma unroll
            for (int msk = 1; msk < 8; msk <<= 1) {
                #pragma unroll
                for (int a = 0; a < 8; a++) pa[a] += __shfl_xor(pa[a], msk);
            }
            sattn[parity][pt][q] = __expf(-fabsf(pa[q] + bscv));
            *(float4*)&sxp[parity][pt][fo]   = make_float4(xr[0],xr[1],xr[2],xr[3]);
            *(float4*)&sxp[parity][pt][fo+4] = make_float4(xr[4],xr[5],xr[6],xr[7]);
        }
        __syncthreads();
        // ---- phase 3: one (a,f) cell per thread, reads buf[parity]
        #pragma unroll 4
        for (int pp = 0; pp < np; pp++) {
            float w = sattn[parity][pp][ca] * sxp[parity][pp][cf];
            csum += w; cmax = fmaxf(cmax, w);
        }
        #pragma unroll
        for (int j = 0; j < 8; j++) cur[j] = nxt[j];
    }

    // ================= fold B: agg -> aggWs (once per graph) =================
    __syncthreads();
    agg[ca*2*FF + cf]      = csum / (float)cnt;   // cnt > 0
    agg[ca*2*FF + FF + cf] = cmax;
    __syncthreads();
    {
        int d = t & 31, grp = t >> 5;             // 16 groups x 64 k
        float acc = 0.f;
        #pragma unroll
        for (int k2 = 0; k2 < 64; k2++) {
            int k = grp*64 + k2;
            acc += agg[k] * Wagg[k*DD + d];
        }
        red[grp][d] = acc;
    }
    __syncthreads();
    if (t < DD) {
        float r = 0.f;
        #pragma unroll
        for (int qq = 0; qq < 16; qq++) r += red[qq][t];
        aggWs[t] = r + beff[t] + shW[t];
    }
    __syncthreads();                              // aggWs visible

    // ================= pass 2 (barrier-free): out = tanh(row@sW + aggWs) =================
    float s1 = 0.f, s2a = 0.f;
    if (pt < cnt) {
        float4 a0 = *(const float4*)&aggWs[d4];
        if (isL0) {
            for (int n = gs + pt; n < gs + cnt; n += CH) {
                float o0,o1,o2,o3;
                embed4(x, Wi, bi, lniw, lnib, n, d4, o0,o1,o2,o3);
                float4 row[8];
                #pragma unroll
                for (int j = 0; j < 8; j++) {
                    int src = (t & 56) | j;
                    row[j].x = __shfl(o0, src, 64); row[j].y = __shfl(o1, src, 64);
                    row[j].z = __shfl(o2, src, 64); row[j].w = __shfl(o3, src, 64);
                }
                float acc0 = a0.x, acc1 = a0.y, acc2 = a0.z, acc3 = a0.w;
                #pragma unroll
                for (int k4 = 0; k4 < 8; k4++) {
                    float hv0 = row[k4].x, hv1 = row[k4].y, hv2 = row[k4].z, hv3 = row[k4].w;
                    int kb = k4*4;
                    float4 w;
                    w = *(const float4*)&sW[kb+0][d4];
                    acc0 += hv0*w.x; acc1 += hv0*w.y; acc2 += hv0*w.z; acc3 += hv0*w.w;
                    w = *(const float4*)&sW[kb+1][d4];
                    acc0 += hv1*w.x; acc1 += hv1*w.y; acc2 += hv1*w.z; acc3 += hv1*w.w;
                    w = *(const float4*)&sW[kb+2][d4];
                    acc0 += hv2*w.x; acc1 += hv2*w.y; acc2 += hv2*w.z; acc3 += hv2*w.w;
                    w = *(const float4*)&sW[kb+3][d4];
                    acc0 += hv3*w.x; acc1 += hv3*w.y; acc2 += hv3*w.z; acc3 += hv3*w.w;
                }
                float4 o;
                o.x = tanh_fast(acc0); o.y = tanh_fast(acc1);
                o.z = tanh_fast(acc2); o.w = tanh_fast(acc3);
                *(float4*)&tbuf[(size_t)n*DD + d4] = o;
                s1  += (o.x + o.y) + (o.z + o.w);
                s2a += (o.x*o.x + o.y*o.y) + (o.z*o.z + o.w*o.w);
            }
        } else {
            float4 rcur[8], rnxt[8];
            {
                const float4* r4 = (const float4*)(inb + (size_t)(gs + pt)*DD);
                #pragma unroll
                for (int j = 0; j < 8; j++) rcur[j] = r4[j];
            }
            for (int n = gs + pt; n < gs + cnt; n += CH) {
                int nn = n + CH;
                int nclamp = (nn < gs + cnt) ? nn : n;
                {
                    const float4* r4 = (const float4*)(inb + (size_t)nclamp*DD);
                    #pragma unroll
                    for (int j = 0; j < 8; j++) rnxt[j] = r4[j];
                }
                float acc0 = a0.x, acc1 = a0.y, acc2 = a0.z, acc3 = a0.w;
                #pragma unroll
                for (int k4 = 0; k4 < 8; k4++) {
                    float hv0 = rcur[k4].x, hv1 = rcur[k4].y, hv2 = rcur[k4].z, hv3 = rcur[k4].w;
                    int kb = k4*4;
                    float4 w;
                    w = *(const float4*)&sW[kb+0][d4];
                    acc0 += hv0*w.x; acc1 += hv0*w.y; acc2 += hv0*w.z; acc3 += hv0*w.w;
                    w = *(const float4*)&sW[kb+1][d4];
                    acc0 += hv1*w.x; acc1 += hv1*w.y; acc2 += hv1*w.z; acc3 += hv1*w.w;
                    w = *(const float4*)&sW[kb+2][d4];
                    acc0 += hv2*w.x; acc1 += hv2*w.y; acc2 += hv2*w.z; acc3 += hv2*w.w;
                    w = *(const float4*)&sW[kb+3][d4];
                    acc0 += hv3*w.x; acc1 += hv3*w.y; acc2 += hv3*w.z; acc3 += hv3*w.w;
                }
                float4 o;
                o.x = tanh_fast(acc0); o.y = tanh_fast(acc1);
                o.z = tanh_fast(acc2); o.w = tanh_fast(acc3);
                *(float4*)&tbuf[(size_t)n*DD + d4] = o;
                s1  += (o.x + o.y) + (o.z + o.w);
                s2a += (o.x*o.x + o.y*o.y) + (o.z*o.z + o.w*o.w);
                #pragma unroll
                for (int j = 0; j < 8; j++) rcur[j] = rnxt[j];
            }
        }
    }
    // stats reduce -> one atomic pair per block
    #pragma unroll
    for (int o = 32; o > 0; o >>= 1) { s1 += __shfl_down(s1, o); s2a += __shfl_down(s2a, o); }
    int wid = t >> 6;
    __syncthreads();
    if ((t & 63) == 0) { rs1[wid] = s1; rs2[wid] = s2a; }
    __syncthreads();
    if (t == 0) {
        float a1 = 0.f, a2 = 0.f;
        #pragma unroll
        for (int qq = 0; qq < 8; qq++) { a1 += rs1[qq]; a2 += rs2[qq]; }
        atomicAdd(&statsO[0], a1);
        atomicAdd(&statsO[1], a2);
    }
}

// ---------------------------------------------------------------- readout: segment mean of gln(tbuf) -> 3x (dense+ln+tanh) -> dot
__global__ __launch_bounds__(256) void k_read(const float* __restrict__ tbuf,
                                              const float* __restrict__ stats,
                                              const float* __restrict__ gw,
                                              const float* __restrict__ gb,
                                              const int* __restrict__ offs,
                                              const float* __restrict__ Wp,
                                              const float* __restrict__ bp,
                                              const float* __restrict__ lnw,
                                              const float* __restrict__ lnb,
                                              const float* __restrict__ Wpo,
                                              const float* __restrict__ bpo,
                                              float* __restrict__ out) {
    int g = blockIdx.x;
    int t = threadIdx.x;
    int d = t & 31, pl = t >> 5;   // 8 point-lanes x 32 dims
    int s0 = offs[g], e0 = offs[g+1];
    float acc = 0.f;
    for (int n = s0 + pl; n < e0; n += 8) acc += tbuf[(size_t)n*DD + d];
    __shared__ float red[8][DD];
    red[pl][d] = acc;
    __syncthreads();
    __shared__ float sv[DD];
    if (t < DD) {
        float r = 0.f;
        #pragma unroll
        for (int qq = 0; qq < 8; qq++) r += red[qq][t];
        const float invM = 1.f/((float)NPTS*DD);
        float m = stats[0]*invM;
        float var = stats[1]*invM - m*m;
        float inv = 1.f/(sqrtf(fmaxf(var, 0.f)) + EPSV);
        float cnt = (float)(e0 - s0);
        float mean = r / fmaxf(cnt, 1.f);
        sv[t] = (e0 > s0) ? (mean - m)*inv*gw[t] + gb[t] : 0.f;
    }
    __syncthreads();
    for (int j = 0; j < 3; j++) {
        float yv = 0.f;
        if (t < DD) {
            float y = bp[j*DD + t];
            #pragma unroll
            for (int i = 0; i < DD; i++) y += sv[i] * Wp[j*DD*DD + i*DD + t];
            float sum = y;
            #pragma unroll
            for (int o = 1; o < 32; o <<= 1) sum += __shfl_xor(sum, o);
            float m = sum * (1.f/DD);
            float c = y - m;
            float sq = c*c;
            #pragma unroll
            for (int o = 1; o < 32; o <<= 1) sq += __shfl_xor(sq, o);
            float var = sq * (1.f/DD);
            yv = tanh_fast(c / sqrtf(var + EPSV) * lnw[j*DD+t] + lnb[j*DD+t]);
        }
        __syncthreads();
        if (t < DD) sv[t] = yv;
        __syncthreads();
    }
    if (t < DD) {
        float p = sv[t] * Wpo[t];
        #pragma unroll
        for (int o = 1; o < 32; o <<= 1) p += __shfl_xor(p, o);
        if (t == 0) out[g] = p + bpo[0];
    }
}

extern "C" void kernel_launch(void* const* d_in, const int* in_sizes, int n_in,
                              void* d_out, int out_size, void* d_ws, size_t ws_size,
                              hipStream_t stream) {
    const float* x     = (const float*)d_in[0];
    const int*   batch = (const int*)  d_in[1];
    const float* Wi    = (const float*)d_in[2];
    const float* bi    = (const float*)d_in[3];
    const float* lni_w = (const float*)d_in[4];
    const float* lni_b = (const float*)d_in[5];
    const float* W_in  = (const float*)d_in[6];
    const float* b_in  = (const float*)d_in[7];
    const float* W_sc  = (const float*)d_in[8];
    const float* b_sc  = (const float*)d_in[9];
    const float* W_out = (const float*)d_in[10];
    const float* b_out = (const float*)d_in[11];
    const float* gln_w = (const float*)d_in[12];
    const float* gln_b = (const float*)d_in[13];
    const float* Wp    = (const float*)d_in[14];
    const float* bp    = (const float*)d_in[15];
    const float* lnp_w = (const float*)d_in[16];
    const float* lnp_b = (const float*)d_in[17];
    const float* Wpo   = (const float*)d_in[18];
    const float* bpo   = (const float*)d_in[19];
    float* out = (float*)d_out;

    float* ws    = (float*)d_ws;
    float* tbuf  = ws;                                  // NPTS*32
    float* stats = tbuf + (size_t)NPTS*DD;              // 32
    float* Weff  = stats + 32;                          // 3*1024
    float* beff  = Weff + 3*DD*DD;                      // 96
    int*   offs  = (int*)(beff + 3*DD);                 // NG+1

    k_setup<<<4, 256, 0, stream>>>(batch, W_in, b_in, W_out, b_out, offs, stats, Weff, beff);

    for (int L = 0; L < 9; ++L) {
        int j = L % 3;
        int pj = (L + 2) % 3;
        const float* st  = L ? stats + 2*(L-1) : nullptr;
        const float* pgw = L ? gln_w + pj*DD : nullptr;
        const float* pgb = L ? gln_b + pj*DD : nullptr;
        k_L<<<NG, NT, 0, stream>>>(
            x, Wi, bi, lni_w, lni_b,
            tbuf, st, pgw, pgb,
            W_in + (size_t)j*DD*FF, b_in + j*FF,
            W_sc + (size_t)j*FF*AA, b_sc + j*AA,
            offs,
            W_out + (size_t)j*HINC*DD + (size_t)96*DD, beff + j*DD,
            Weff + (size_t)j*DD*DD, tbuf, stats + 2*L, (L == 0) ? 1 : 0);
    }
    k_read<<<NG, 256, 0, stream>>>(tbuf, stats + 16, gln_w + 2*DD, gln_b + 2*DD,
                                   offs, Wp, bp, lnp_w, lnp_b, Wpo, bpo, out);
}